// Round 9
// baseline (126.772 us; speedup 1.0000x reference)
//
#include <hip/hip_runtime.h>
#include <math.h>

#define Bn 4
#define Tn 4096
#define Cn 1024
#define Hn 64

typedef __attribute__((ext_vector_type(8))) short short8;
typedef __attribute__((ext_vector_type(4))) float floatx4;
typedef unsigned short ushort_t;

// 0.125 (H^-0.5) * log2(e): folded into Q so attn uses native exp2
#define QSCALE 0.1803368801111204f

// Compiler fence (R7/R8 lesson: hipcc re-serializes register load batches to
// minimal pressure; fence keeps issued batches batched).
#define ILP_FENCE() asm volatile("" ::: "memory")

// Async global->LDS DMA, 16B per lane, dest = uniform base + lane*16.
// Zero VGPR cost, deep vmcnt queue: hipcc CANNOT re-serialize these (R8's
// residual gap: reg-staged loads kept qkv at ~300B/wave in flight).
__device__ __forceinline__ void dma16(const void* g, void* l) {
  __builtin_amdgcn_global_load_lds(
      (const __attribute__((address_space(1))) void*)g,
      (__attribute__((address_space(3))) void*)l, 16, 0, 0);
}

__device__ __forceinline__ ushort_t f2bf(float f) {       // RNE
  union { float f; unsigned u; } v; v.f = f;
  unsigned r = v.u + 0x7FFFu + ((v.u >> 16) & 1u);
  return (ushort_t)(r >> 16);
}
__device__ __forceinline__ ushort_t f2bf_hu(float f) {    // round-half-up (P only)
  union { float f; unsigned u; } v; v.f = f;
  return (ushort_t)((v.u + 0x8000u) >> 16);
}
__device__ __forceinline__ float bf2f(ushort_t h) {
  union { unsigned u; float f; } v; v.u = ((unsigned)h) << 16; return v.f;
}

// ---------------------------------------------------------------------------
// Layouts (lane = (quad=lane>>4, col=lane&15); addresses = base + lane*16B):
//  Qf/Kf[b][s=t/16][half=h/32]: lane holds h = half*32+quad*8+e for t=s*16+col.
//  Vf[b][i=t/64][ht=h/16][kh]: lane reg e holds V[t=i*64+pi2(kh,quad,e)][ht*16+col]
//    with pi2 = 32*kh + 16*(e>>2) + 4*quad + (e&3). Matches the SWAPPED-QK
//    register layout of P, so P feeds PV's A-fragment from registers (no LDS).
//  Wf[m][g=c/32][nt=h/16]: lane holds W[c=g*32+quad*8+e][h=nt*16+col].
// R9 qkv: x staged f32 via global_load_lds with PRE-SWIZZLED source
// (global chunk c of row r -> LDS chunk c ^ (r&7); involution, applied again
// on read). 16-row blocks (R5-verified epilogue), grid 1024.
// ---------------------------------------------------------------------------

// W^T -> fragment-major bf16. grid = 96 (m*32+g), 256 threads.
__global__ __launch_bounds__(256) void wf_kernel(
    const float* __restrict__ Wq, const float* __restrict__ Wk,
    const float* __restrict__ Wv, ushort_t* __restrict__ Wf)
{
  __shared__ float ws[32][65];
  const int tid = threadIdx.x;
  const int m = blockIdx.x >> 5;
  const int g = blockIdx.x & 31;
  const float* W = (m == 0) ? Wq : (m == 1) ? Wk : Wv;
  const float4* src = (const float4*)(W + (size_t)g * 32 * Hn);
#pragma unroll
  for (int it = 0; it < 2; ++it) {
    int i4 = it * 256 + tid;
    float4 v = src[i4];
    int c = i4 >> 4, h = (i4 & 15) * 4;
    ws[c][h] = v.x; ws[c][h + 1] = v.y; ws[c][h + 2] = v.z; ws[c][h + 3] = v.w;
  }
  __syncthreads();
  const int nt = tid >> 6, lane = tid & 63;
  const int col = lane & 15, quad = lane >> 4;
  ushort_t t[8];
#pragma unroll
  for (int e = 0; e < 8; ++e) t[e] = f2bf(ws[quad * 8 + e][nt * 16 + col]);
  *(short8*)(Wf + ((size_t)((m * 32 + g) * 4 + nt) * 64 + lane) * 8) = *(short8*)t;
}

// ---------------------------------------------------------------------------
// QKV projection. grid = 1024 x 256; block owns 16 rows, 4 waves K-split
// (256 ch each). x slice DMA'd to LDS as f32 (16 x global_load_lds_dwordx4
// per wave, 16KB in flight -- HW-queued, compiler can't serialize). Source
// pre-swizzled (chunk c -> c^(r&7)) so the row-major af read is conflict-free
// with a LINEAR DMA dest. af read: 2 swizzled ds_read_b128 + RNE cvt in reg.
// Wf: R8's fenced 12-load batches. Epilogue: R5's verified 16-row version.
// LDS 64KB (red/img overlay xs after it dies) -> 2 blocks/CU.
// ---------------------------------------------------------------------------
__global__ __launch_bounds__(256, 2) void qkv_proj_kernel(
    const float* __restrict__ x, const ushort_t* __restrict__ Wf,
    ushort_t* __restrict__ Qf, ushort_t* __restrict__ Kf,
    ushort_t* __restrict__ Vf)
{
  __shared__ __align__(16) char smem[65536];
  // xs_f32: [4 wv][16 row][256 ch] f32, chunk-swizzled (64 KB)
  ushort_t* red = (ushort_t*)smem;              // overlays xs: [12][4][64][4] (24576 B)
  ushort_t* img = (ushort_t*)(smem + 24576);    // Q[1024] K[1024] V[1024] (6144 B)

  const int tid  = threadIdx.x;
  const int wv   = tid >> 6;
  const int lane = tid & 63;
  const int col  = lane & 15;
  const int quad = lane >> 4;
  const int blk  = blockIdx.x;
  const int row0 = blk * 16;

  // ---- DMA wave's x slice (16 rows x 256 ch f32) to LDS, pre-swizzled ----
#pragma unroll
  for (int r = 0; r < 16; ++r) {
    const float* gp = x + (size_t)(row0 + r) * Cn + wv * 256 + ((lane ^ (r & 7)) << 2);
    void* lp = smem + wv * 16384 + r * 1024;    // wave-uniform dest base
    dma16(gp, lp);
  }
  asm volatile("s_waitcnt vmcnt(0)" ::: "memory");   // DMAs landed (own-wave reads)
  __builtin_amdgcn_sched_barrier(0);

  floatx4 acc[3][4];
#pragma unroll
  for (int m = 0; m < 3; ++m)
#pragma unroll
    for (int nt = 0; nt < 4; ++nt) {
      acc[m][nt][0] = 0.f; acc[m][nt][1] = 0.f;
      acc[m][nt][2] = 0.f; acc[m][nt][3] = 0.f;
    }

  // ---- K-loop: 8 x 32ch; fenced 12-load Wf batch + swizzled af read ----
#pragma unroll
  for (int ch = 0; ch < 8; ++ch) {
    const int gg = wv * 8 + ch;                 // global 32-ch chunk
    short8 bf[12];
#pragma unroll
    for (int k = 0; k < 12; ++k) {
      const int m_ = k >> 2, nt_ = k & 3;
      bf[k] = *(const short8*)(Wf + ((size_t)((m_ * 32 + gg) * 4 + nt_) * 64 + lane) * 8);
    }
    // af: row col, slice-local chunks c0,c0+1 (swizzled), f32 -> bf16 RNE
    const int c0 = ch * 8 + quad * 2;
    float4 va = *(const float4*)(smem + wv * 16384 + col * 1024 + ((c0 ^ (col & 7)) << 4));
    float4 vb = *(const float4*)(smem + wv * 16384 + col * 1024 + (((c0 + 1) ^ (col & 7)) << 4));
    ILP_FENCE();   // 12 global + 2 LDS loads in flight before compute
    ushort_t t[8];
    t[0] = f2bf(va.x); t[1] = f2bf(va.y); t[2] = f2bf(va.z); t[3] = f2bf(va.w);
    t[4] = f2bf(vb.x); t[5] = f2bf(vb.y); t[6] = f2bf(vb.z); t[7] = f2bf(vb.w);
    short8 af = *(short8*)t;
#pragma unroll
    for (int k = 0; k < 12; ++k)
      acc[k >> 2][k & 3] = __builtin_amdgcn_mfma_f32_16x16x32_bf16(af, bf[k], acc[k >> 2][k & 3], 0, 0, 0);
  }
  __syncthreads();   // xs reads done everywhere; safe to overlay red

  // ---- dump ALL partials to LDS (static acc indices; lane-contiguous 8B) ----
#pragma unroll
  for (int m = 0; m < 3; ++m)
#pragma unroll
    for (int nt = 0; nt < 4; ++nt) {
      const int p = m * 4 + nt;
      ushort4 u;
      u.x = f2bf(acc[m][nt][0]); u.y = f2bf(acc[m][nt][1]);
      u.z = f2bf(acc[m][nt][2]); u.w = f2bf(acc[m][nt][3]);
      *(ushort4*)&red[((p * 4 + wv) * 64 + lane) * 4] = u;
    }
  __syncthreads();

  // ---- wave wv reduces p in [3wv, 3wv+3) from LDS; writes frag-images ----
#pragma unroll
  for (int pp = 0; pp < 3; ++pp) {
    const int p = wv * 3 + pp;
    ushort4 w0 = *(const ushort4*)&red[((p * 4 + 0) * 64 + lane) * 4];
    ushort4 w1 = *(const ushort4*)&red[((p * 4 + 1) * 64 + lane) * 4];
    ushort4 w2 = *(const ushort4*)&red[((p * 4 + 2) * 64 + lane) * 4];
    ushort4 w3 = *(const ushort4*)&red[((p * 4 + 3) * 64 + lane) * 4];
    float v[4];
    v[0] = (bf2f(w0.x) + bf2f(w1.x)) + (bf2f(w2.x) + bf2f(w3.x));
    v[1] = (bf2f(w0.y) + bf2f(w1.y)) + (bf2f(w2.y) + bf2f(w3.y));
    v[2] = (bf2f(w0.z) + bf2f(w1.z)) + (bf2f(w2.z) + bf2f(w3.z));
    v[3] = (bf2f(w0.w) + bf2f(w1.w)) + (bf2f(w2.w) + bf2f(w3.w));
    const int m = p >> 2, nt = p & 3;
#pragma unroll
    for (int r = 0; r < 4; ++r) {
      const int tlq = quad * 4 + r;
      if (m == 2) {
        // V image: slot (lane = quad*16+col, e-low = r); e-high from g&1 at copy-out
        img[2048 + nt * 256 + (quad * 16 + col) * 4 + r] = f2bf(v[r]);
      } else {
        const int h = nt * 16 + col;
        const int idx = (h >> 5) * 512 + ((h >> 3) & 3) * 128 + tlq * 8 + (h & 7);
        img[m * 1024 + idx] = f2bf(m == 0 ? v[r] * QSCALE : v[r]);
      }
    }
  }
  __syncthreads();

  // ---- coalesced copy-out ----
  {
    const int b = blk >> 8, g = blk & 255;
    const size_t qg = (size_t)(b * 256 + g) * 1024 + tid * 4;
    *(uint2*)(Qf + qg) = *(const uint2*)&img[tid * 4];
    *(uint2*)(Kf + qg) = *(const uint2*)&img[1024 + tid * 4];
    const int ht = tid >> 6;
    const size_t vg = ((size_t)(b * 64 + (g >> 2)) * 8 + ht * 2 + ((g >> 1) & 1)) * 512
                      + (tid & 63) * 8 + (g & 1) * 4;
    *(uint2*)(Vf + vg) = *(const uint2*)&img[2048 + ht * 256 + (tid & 63) * 4];
  }
}

// ---------------------------------------------------------------------------
// Flash attention (R8 verbatim -- current best). grid = B*128 (32-row
// q-tiles), balanced g remap, 4 waves stride 64-key tiles with private (O,l).
// Swapped QK^T keeps P in registers; one fenced 16-load K/V batch per tile;
// zero barriers in the main loop.
// ---------------------------------------------------------------------------
__global__ __launch_bounds__(256, 2) void attn_kernel(
    const ushort_t* __restrict__ Qf, const ushort_t* __restrict__ Kf,
    const ushort_t* __restrict__ Vf, float* __restrict__ out)
{
  __shared__ __align__(16) float Om[4][2][16][68];
  __shared__ __align__(16) float Ml[4][2][16];

  const int tid  = threadIdx.x;
  const int wv   = tid >> 6;
  const int lane = tid & 63;
  const int col  = lane & 15;
  const int quad = lane >> 4;
  const int b   = blockIdx.x & 3;
  const int idx = blockIdx.x >> 2;                          // 0..127
  const int g   = (idx < 64) ? (127 - 2 * idx) : (2 * (idx - 64));  // balanced remap

  short8 qf[2][2];
#pragma unroll
  for (int sub = 0; sub < 2; ++sub)
#pragma unroll
    for (int half = 0; half < 2; ++half)
      qf[sub][half] = *(const short8*)(Qf + (size_t)(b * 256 + 2 * g + sub) * 1024 + half * 512 + lane * 8);

  const ushort_t* Kbase = Kf + (size_t)b * 256 * 1024;
  const ushort_t* Vbase = Vf + (size_t)b * 64 * 8 * 512;

  short8 ones;
#pragma unroll
  for (int e = 0; e < 8; ++e) ones[e] = (short)0x3F80;  // bf16 1.0

  floatx4 o[2][4], ol[2];
#pragma unroll
  for (int sub = 0; sub < 2; ++sub) {
#pragma unroll
    for (int ht = 0; ht < 4; ++ht) { o[sub][ht][0]=0.f; o[sub][ht][1]=0.f; o[sub][ht][2]=0.f; o[sub][ht][3]=0.f; }
    ol[sub][0]=0.f; ol[sub][1]=0.f; ol[sub][2]=0.f; ol[sub][3]=0.f;
  }

  const int ntile = ((g * 32 + 31) >> 6) + 1;
  const int dtile = ntile - 1;

  for (int i = wv; i < ntile; i += 4) {
    // ---- one fenced batch: all 8 K + 8 V fragments of tile i in flight ----
    short8 kf[8], vf[8];
#pragma unroll
    for (int kt = 0; kt < 4; ++kt) {
      const ushort_t* kp = Kbase + (size_t)i * 4096 + kt * 1024 + lane * 8;
      kf[kt * 2]     = *(const short8*)(kp);
      kf[kt * 2 + 1] = *(const short8*)(kp + 512);
    }
#pragma unroll
    for (int ht = 0; ht < 4; ++ht) {
#pragma unroll
      for (int kh = 0; kh < 2; ++kh)
        vf[ht * 2 + kh] = *(const short8*)(Vbase + ((size_t)i * 8 + ht * 2 + kh) * 512 + lane * 8);
    }
    ILP_FENCE();

    // S^T = K Q^T (swapped): lane(quad,col) reg r of s[sub][kt] holds
    // S[key = 64i+16kt+4quad+r][q = g*32+sub*16+col]
    floatx4 s[2][4];
    __builtin_amdgcn_s_setprio(1);
#pragma unroll
    for (int sub = 0; sub < 2; ++sub)
#pragma unroll
      for (int kt = 0; kt < 4; ++kt) {
        floatx4 c; c[0]=0.f; c[1]=0.f; c[2]=0.f; c[3]=0.f;
        c = __builtin_amdgcn_mfma_f32_16x16x32_bf16(kf[kt * 2],     qf[sub][0], c, 0, 0, 0);
        c = __builtin_amdgcn_mfma_f32_16x16x32_bf16(kf[kt * 2 + 1], qf[sub][1], c, 0, 0, 0);
        s[sub][kt] = c;
      }
    __builtin_amdgcn_s_setprio(0);

    if (i == dtile) {   // causal mask on diagonal tile (exp2(-inf)=0)
#pragma unroll
      for (int sub = 0; sub < 2; ++sub)
#pragma unroll
        for (int kt = 0; kt < 4; ++kt)
#pragma unroll
          for (int r = 0; r < 4; ++r)
            if (64 * i + kt * 16 + quad * 4 + r > g * 32 + sub * 16 + col)
              s[sub][kt][r] = -INFINITY;
    }

#pragma unroll
    for (int sub = 0; sub < 2; ++sub)
#pragma unroll
      for (int kt = 0; kt < 4; ++kt)
#pragma unroll
        for (int r = 0; r < 4; ++r)
          s[sub][kt][r] = __builtin_amdgcn_exp2f(s[sub][kt][r]);

    // pack P to bf16 A-fragments IN REGISTERS (key order = pi2, V matches)
    short8 pf[2][2];
#pragma unroll
    for (int sub = 0; sub < 2; ++sub)
#pragma unroll
      for (int kh = 0; kh < 2; ++kh) {
        ushort_t tmp[8];
#pragma unroll
        for (int half = 0; half < 2; ++half)
#pragma unroll
          for (int r = 0; r < 4; ++r)
            tmp[half * 4 + r] = f2bf_hu(s[sub][2 * kh + half][r]);
        pf[sub][kh] = *(short8*)tmp;
      }

    // O += P V (V pre-permuted to pi2); l += P 1
    __builtin_amdgcn_s_setprio(1);
#pragma unroll
    for (int sub = 0; sub < 2; ++sub) {
#pragma unroll
      for (int ht = 0; ht < 4; ++ht) {
        o[sub][ht] = __builtin_amdgcn_mfma_f32_16x16x32_bf16(pf[sub][0], vf[ht * 2],     o[sub][ht], 0, 0, 0);
        o[sub][ht] = __builtin_amdgcn_mfma_f32_16x16x32_bf16(pf[sub][1], vf[ht * 2 + 1], o[sub][ht], 0, 0, 0);
      }
      ol[sub] = __builtin_amdgcn_mfma_f32_16x16x32_bf16(pf[sub][0], ones, ol[sub], 0, 0, 0);
      ol[sub] = __builtin_amdgcn_mfma_f32_16x16x32_bf16(pf[sub][1], ones, ol[sub], 0, 0, 0);
    }
    __builtin_amdgcn_s_setprio(0);
  }

  // ---- merge 4 waves' partials (plain sums; max-free) ----
#pragma unroll
  for (int sub = 0; sub < 2; ++sub) {
#pragma unroll
    for (int ht = 0; ht < 4; ++ht)
#pragma unroll
      for (int r = 0; r < 4; ++r)
        Om[wv][sub][quad * 4 + r][ht * 16 + col] = o[sub][ht][r];
    if (col == 0) {
#pragma unroll
      for (int r = 0; r < 4; ++r) Ml[wv][sub][quad * 4 + r] = ol[sub][r];
    }
  }
  __syncthreads();

  const int rr = tid >> 4, h4 = (tid & 15) * 4;
#pragma unroll
  for (int sub = 0; sub < 2; ++sub) {
    float L = (Ml[0][sub][rr] + Ml[1][sub][rr]) + (Ml[2][sub][rr] + Ml[3][sub][rr]);
    float4 a; a.x = 0.f; a.y = 0.f; a.z = 0.f; a.w = 0.f;
#pragma unroll
    for (int w = 0; w < 4; ++w) {
      float4 ov = *(const float4*)&Om[w][sub][rr][h4];
      a.x += ov.x; a.y += ov.y; a.z += ov.z; a.w += ov.w;
    }
    float inv = 1.f / L;
    a.x *= inv; a.y *= inv; a.z *= inv; a.w *= inv;
    *(float4*)(out + (size_t)(b * Tn + g * 32 + sub * 16 + rr) * Hn + h4) = a;
  }
}

extern "C" void kernel_launch(void* const* d_in, const int* in_sizes, int n_in,
                              void* d_out, int out_size, void* d_ws, size_t ws_size,
                              hipStream_t stream) {
  const float* x  = (const float*)d_in[0];
  const float* Wq = (const float*)d_in[1];
  const float* Wk = (const float*)d_in[2];
  const float* Wv = (const float*)d_in[3];
  float* out = (float*)d_out;

  ushort_t* Qf = (ushort_t*)d_ws;                   // 2 MB frag-major (pre-scaled)
  ushort_t* Kf = Qf + (size_t)Bn * Tn * Hn;         // 2 MB
  ushort_t* Vf = Kf + (size_t)Bn * Tn * Hn;         // 2 MB (pi2-permuted keys)
  ushort_t* Wf = Vf + (size_t)Bn * Tn * Hn;         // 384 KB

  wf_kernel<<<dim3(96), dim3(256), 0, stream>>>(Wq, Wk, Wv, Wf);
  qkv_proj_kernel<<<dim3(1024), dim3(256), 0, stream>>>(x, Wf, Qf, Kf, Vf);
  attn_kernel<<<dim3(Bn * 128), dim3(256), 0, stream>>>(Qf, Kf, Vf, out);
}

// Round 10
// 125.675 us; speedup vs baseline: 1.0087x; 1.0087x over previous
//
#include <hip/hip_runtime.h>
#include <math.h>

#define Bn 4
#define Tn 4096
#define Cn 1024
#define Hn 64

typedef __attribute__((ext_vector_type(8))) short short8;
typedef __attribute__((ext_vector_type(4))) float floatx4;
typedef unsigned short ushort_t;

// 0.125 (H^-0.5) * log2(e): folded into Q so attn uses native exp2
#define QSCALE 0.1803368801111204f

// Compiler fence (R7/R8 lesson: hipcc re-serializes register load batches to
// minimal pressure; fence keeps issued batches batched).
#define ILP_FENCE() asm volatile("" ::: "memory")

__device__ __forceinline__ ushort_t f2bf(float f) {       // RNE
  union { float f; unsigned u; } v; v.f = f;
  unsigned r = v.u + 0x7FFFu + ((v.u >> 16) & 1u);
  return (ushort_t)(r >> 16);
}
__device__ __forceinline__ ushort_t f2bf_hu(float f) {    // round-half-up (P only)
  union { float f; unsigned u; } v; v.f = f;
  return (ushort_t)((v.u + 0x8000u) >> 16);
}
__device__ __forceinline__ float bf2f(ushort_t h) {
  union { unsigned u; float f; } v; v.u = ((unsigned)h) << 16; return v.f;
}

// ---------------------------------------------------------------------------
// Layouts (lane = (quad=lane>>4, col=lane&15); addresses = base + lane*16B):
//  Qf/Kf[b][s=t/16][half=h/32]: lane holds h = half*32+quad*8+e for t=s*16+col.
//  Vf[b][i=t/64][ht=h/16][kh]: lane reg e holds V[t=i*64+pi2(kh,quad,e)][ht*16+col]
//    with pi2 = 32*kh + 16*(e>>2) + 4*quad + (e&3). Matches the SWAPPED-QK
//    register layout of P, so P feeds PV's A-fragment from registers (no LDS).
//  Wf[m][g=c/32][nt=h/16]: lane holds W[c=g*32+quad*8+e][h=nt*16+col].
// R10 qkv: 64-ROW BLOCKS (grid 256, 1 block/CU, lb(256,1)). Mechanism: Wf
// L2 traffic per block is fixed (384 KB full-weight read); only rows/block
// amortizes it. 64 rows halves total Wf traffic 197->98 MB and each fenced
// 12KB Wf batch now feeds 48 MFMAs (2x intensity per wait event). acc=192
// VGPR fits the 512-reg budget at 1 wave/SIMD; R5 proved TLP is not the
// binding resource for this kernel.
// ---------------------------------------------------------------------------

// W^T -> fragment-major bf16. grid = 96 (m*32+g), 256 threads.
__global__ __launch_bounds__(256) void wf_kernel(
    const float* __restrict__ Wq, const float* __restrict__ Wk,
    const float* __restrict__ Wv, ushort_t* __restrict__ Wf)
{
  __shared__ float ws[32][65];
  const int tid = threadIdx.x;
  const int m = blockIdx.x >> 5;
  const int g = blockIdx.x & 31;
  const float* W = (m == 0) ? Wq : (m == 1) ? Wk : Wv;
  const float4* src = (const float4*)(W + (size_t)g * 32 * Hn);
#pragma unroll
  for (int it = 0; it < 2; ++it) {
    int i4 = it * 256 + tid;
    float4 v = src[i4];
    int c = i4 >> 4, h = (i4 & 15) * 4;
    ws[c][h] = v.x; ws[c][h + 1] = v.y; ws[c][h + 2] = v.z; ws[c][h + 3] = v.w;
  }
  __syncthreads();
  const int nt = tid >> 6, lane = tid & 63;
  const int col = lane & 15, quad = lane >> 4;
  ushort_t t[8];
#pragma unroll
  for (int e = 0; e < 8; ++e) t[e] = f2bf(ws[quad * 8 + e][nt * 16 + col]);
  *(short8*)(Wf + ((size_t)((m * 32 + g) * 4 + nt) * 64 + lane) * 8) = *(short8*)t;
}

// ---------------------------------------------------------------------------
// QKV projection. grid = 256 x 256; block owns 64 rows (4 subtiles), 4 waves
// K-split (256 ch each). x staged bf16 to LDS in 16-deep fenced batches.
// K-loop: per ch, one fenced 12-load Wf batch + 4 LDS af reads -> 48 MFMAs.
// Epilogue: 48 partials to LDS bf16 (STATIC acc indexing), wave wv reduces
// subtile wv, frag-image staging, coalesced copy-out. LDS 132 KB, 1 block/CU.
// ---------------------------------------------------------------------------
__global__ __launch_bounds__(256, 1) void qkv_proj_kernel(
    const float* __restrict__ x, const ushort_t* __restrict__ Wf,
    ushort_t* __restrict__ Qf, ushort_t* __restrict__ Kf,
    ushort_t* __restrict__ Vf)
{
  __shared__ __align__(16) char smem[135168];
  ushort_t* xs  = (ushort_t*)smem;              // [4 wv][64 row][264] bf16 (135168 B)
  ushort_t* red = (ushort_t*)smem;              // overlays xs: [48][4][64][4] (98304 B)
  ushort_t* img = (ushort_t*)(smem + 98304);    // Q[4][1024] K[4][1024] V[4096] (24576 B)

  const int tid  = threadIdx.x;
  const int wv   = tid >> 6;
  const int lane = tid & 63;
  const int col  = lane & 15;
  const int quad = lane >> 4;
  const int blk  = blockIdx.x;
  const int row0 = blk * 64;

  // ---- stage wave's x slice (64 rows x 256 ch): 4 fenced 16-load batches ----
#pragma unroll
  for (int b4 = 0; b4 < 4; ++b4) {
    float4 v[16];
#pragma unroll
    for (int jj = 0; jj < 16; ++jj)
      v[jj] = *(const float4*)(x + (size_t)(row0 + b4 * 16 + jj) * Cn + wv * 256 + lane * 4);
    ILP_FENCE();   // all 16 loads issued & live before any LDS store
#pragma unroll
    for (int jj = 0; jj < 16; ++jj) {
      ushort4 u;
      u.x = f2bf(v[jj].x); u.y = f2bf(v[jj].y); u.z = f2bf(v[jj].z); u.w = f2bf(v[jj].w);
      *(ushort4*)(xs + (wv * 64 + b4 * 16 + jj) * 264 + lane * 4) = u;
    }
  }
  // wave reads only its own slice -> no barrier (lgkmcnt orders same-wave LDS)

  floatx4 acc[4][12];
#pragma unroll
  for (int sub = 0; sub < 4; ++sub)
#pragma unroll
    for (int k = 0; k < 12; ++k) {
      acc[sub][k][0] = 0.f; acc[sub][k][1] = 0.f;
      acc[sub][k][2] = 0.f; acc[sub][k][3] = 0.f;
    }

  // ---- K-loop: 8 x 32ch; fenced 12-load Wf batch feeds 48 MFMAs ----
#pragma unroll
  for (int ch = 0; ch < 8; ++ch) {
    const int gg = wv * 8 + ch;                 // global 32-ch chunk
    short8 bf[12];
#pragma unroll
    for (int k = 0; k < 12; ++k) {
      const int m_ = k >> 2, nt_ = k & 3;
      bf[k] = *(const short8*)(Wf + ((size_t)((m_ * 32 + gg) * 4 + nt_) * 64 + lane) * 8);
    }
    short8 af[4];
#pragma unroll
    for (int sub = 0; sub < 4; ++sub)
      af[sub] = *(const short8*)(xs + (wv * 64 + sub * 16 + col) * 264 + ch * 32 + quad * 8);
    ILP_FENCE();   // 12 global + 4 LDS loads all in flight before compute
#pragma unroll
    for (int k = 0; k < 12; ++k)
#pragma unroll
      for (int sub = 0; sub < 4; ++sub)
        acc[sub][k] = __builtin_amdgcn_mfma_f32_16x16x32_bf16(af[sub], bf[k], acc[sub][k], 0, 0, 0);
  }
  __syncthreads();   // xs reads done everywhere; safe to overlay red

  // ---- dump ALL partials to LDS (static acc indices; lane-contiguous 8B) ----
#pragma unroll
  for (int sub = 0; sub < 4; ++sub)
#pragma unroll
    for (int k = 0; k < 12; ++k) {
      const int p = sub * 12 + k;
      ushort4 u;
      u.x = f2bf(acc[sub][k][0]); u.y = f2bf(acc[sub][k][1]);
      u.z = f2bf(acc[sub][k][2]); u.w = f2bf(acc[sub][k][3]);
      *(ushort4*)&red[((p * 4 + wv) * 64 + lane) * 4] = u;
    }
  __syncthreads();

  // ---- wave wv reduces its own subtile (p in [12wv, 12wv+12)) ----
#pragma unroll
  for (int pp = 0; pp < 12; ++pp) {
    const int p = wv * 12 + pp;               // sub == wv
    ushort4 w0 = *(const ushort4*)&red[((p * 4 + 0) * 64 + lane) * 4];
    ushort4 w1 = *(const ushort4*)&red[((p * 4 + 1) * 64 + lane) * 4];
    ushort4 w2 = *(const ushort4*)&red[((p * 4 + 2) * 64 + lane) * 4];
    ushort4 w3 = *(const ushort4*)&red[((p * 4 + 3) * 64 + lane) * 4];
    float v[4];
    v[0] = (bf2f(w0.x) + bf2f(w1.x)) + (bf2f(w2.x) + bf2f(w3.x));
    v[1] = (bf2f(w0.y) + bf2f(w1.y)) + (bf2f(w2.y) + bf2f(w3.y));
    v[2] = (bf2f(w0.z) + bf2f(w1.z)) + (bf2f(w2.z) + bf2f(w3.z));
    v[3] = (bf2f(w0.w) + bf2f(w1.w)) + (bf2f(w2.w) + bf2f(w3.w));
    const int m = pp >> 2, nt = pp & 3;
#pragma unroll
    for (int r = 0; r < 4; ++r) {
      const int tlq = quad * 4 + r;
      if (m == 2) {
        // V image, pi2: local key 16*wv+4*quad+r -> region (nt, kh=wv>>1),
        // lane (quad,col), element e = (wv&1)*4 + r
        img[8192 + nt * 1024 + (wv >> 1) * 512 + (quad * 16 + col) * 8 + (wv & 1) * 4 + r] = f2bf(v[r]);
      } else {
        const int h = nt * 16 + col;
        const int idx = (h >> 5) * 512 + ((h >> 3) & 3) * 128 + tlq * 8 + (h & 7);
        img[m * 4096 + wv * 1024 + idx] = f2bf(m == 0 ? v[r] * QSCALE : v[r]);
      }
    }
  }
  __syncthreads();

  // ---- coalesced copy-out ----
  {
    const int b = blk >> 6, gp = blk & 63;    // 64-row index within batch
#pragma unroll
    for (int sub = 0; sub < 4; ++sub) {
      const size_t qg = (size_t)(b * 256 + gp * 4 + sub) * 1024 + tid * 4;
      *(uint2*)(Qf + qg) = *(const uint2*)&img[sub * 1024 + tid * 4];
      *(uint2*)(Kf + qg) = *(const uint2*)&img[4096 + sub * 1024 + tid * 4];
    }
    // V: one full 64-key tile (i = gp), 4096 ushorts contiguous in pi2 order
    const size_t vbase = ((size_t)(b * 64 + gp) * 8) * 512;
    *(short8*)(Vf + vbase + tid * 8)        = *(const short8*)&img[8192 + tid * 8];
    *(short8*)(Vf + vbase + 2048 + tid * 8) = *(const short8*)&img[8192 + 2048 + tid * 8];
  }
}

// ---------------------------------------------------------------------------
// Flash attention (R8 verbatim -- current best). grid = B*128 (32-row
// q-tiles), balanced g remap, 4 waves stride 64-key tiles with private (O,l).
// Swapped QK^T keeps P in registers; one fenced 16-load K/V batch per tile;
// zero barriers in the main loop.
// ---------------------------------------------------------------------------
__global__ __launch_bounds__(256, 2) void attn_kernel(
    const ushort_t* __restrict__ Qf, const ushort_t* __restrict__ Kf,
    const ushort_t* __restrict__ Vf, float* __restrict__ out)
{
  __shared__ __align__(16) float Om[4][2][16][68];
  __shared__ __align__(16) float Ml[4][2][16];

  const int tid  = threadIdx.x;
  const int wv   = tid >> 6;
  const int lane = tid & 63;
  const int col  = lane & 15;
  const int quad = lane >> 4;
  const int b   = blockIdx.x & 3;
  const int idx = blockIdx.x >> 2;                          // 0..127
  const int g   = (idx < 64) ? (127 - 2 * idx) : (2 * (idx - 64));  // balanced remap

  short8 qf[2][2];
#pragma unroll
  for (int sub = 0; sub < 2; ++sub)
#pragma unroll
    for (int half = 0; half < 2; ++half)
      qf[sub][half] = *(const short8*)(Qf + (size_t)(b * 256 + 2 * g + sub) * 1024 + half * 512 + lane * 8);

  const ushort_t* Kbase = Kf + (size_t)b * 256 * 1024;
  const ushort_t* Vbase = Vf + (size_t)b * 64 * 8 * 512;

  short8 ones;
#pragma unroll
  for (int e = 0; e < 8; ++e) ones[e] = (short)0x3F80;  // bf16 1.0

  floatx4 o[2][4], ol[2];
#pragma unroll
  for (int sub = 0; sub < 2; ++sub) {
#pragma unroll
    for (int ht = 0; ht < 4; ++ht) { o[sub][ht][0]=0.f; o[sub][ht][1]=0.f; o[sub][ht][2]=0.f; o[sub][ht][3]=0.f; }
    ol[sub][0]=0.f; ol[sub][1]=0.f; ol[sub][2]=0.f; ol[sub][3]=0.f;
  }

  const int ntile = ((g * 32 + 31) >> 6) + 1;
  const int dtile = ntile - 1;

  for (int i = wv; i < ntile; i += 4) {
    // ---- one fenced batch: all 8 K + 8 V fragments of tile i in flight ----
    short8 kf[8], vf[8];
#pragma unroll
    for (int kt = 0; kt < 4; ++kt) {
      const ushort_t* kp = Kbase + (size_t)i * 4096 + kt * 1024 + lane * 8;
      kf[kt * 2]     = *(const short8*)(kp);
      kf[kt * 2 + 1] = *(const short8*)(kp + 512);
    }
#pragma unroll
    for (int ht = 0; ht < 4; ++ht) {
#pragma unroll
      for (int kh = 0; kh < 2; ++kh)
        vf[ht * 2 + kh] = *(const short8*)(Vbase + ((size_t)i * 8 + ht * 2 + kh) * 512 + lane * 8);
    }
    ILP_FENCE();

    // S^T = K Q^T (swapped): lane(quad,col) reg r of s[sub][kt] holds
    // S[key = 64i+16kt+4quad+r][q = g*32+sub*16+col]
    floatx4 s[2][4];
    __builtin_amdgcn_s_setprio(1);
#pragma unroll
    for (int sub = 0; sub < 2; ++sub)
#pragma unroll
      for (int kt = 0; kt < 4; ++kt) {
        floatx4 c; c[0]=0.f; c[1]=0.f; c[2]=0.f; c[3]=0.f;
        c = __builtin_amdgcn_mfma_f32_16x16x32_bf16(kf[kt * 2],     qf[sub][0], c, 0, 0, 0);
        c = __builtin_amdgcn_mfma_f32_16x16x32_bf16(kf[kt * 2 + 1], qf[sub][1], c, 0, 0, 0);
        s[sub][kt] = c;
      }
    __builtin_amdgcn_s_setprio(0);

    if (i == dtile) {   // causal mask on diagonal tile (exp2(-inf)=0)
#pragma unroll
      for (int sub = 0; sub < 2; ++sub)
#pragma unroll
        for (int kt = 0; kt < 4; ++kt)
#pragma unroll
          for (int r = 0; r < 4; ++r)
            if (64 * i + kt * 16 + quad * 4 + r > g * 32 + sub * 16 + col)
              s[sub][kt][r] = -INFINITY;
    }

#pragma unroll
    for (int sub = 0; sub < 2; ++sub)
#pragma unroll
      for (int kt = 0; kt < 4; ++kt)
#pragma unroll
        for (int r = 0; r < 4; ++r)
          s[sub][kt][r] = __builtin_amdgcn_exp2f(s[sub][kt][r]);

    // pack P to bf16 A-fragments IN REGISTERS (key order = pi2, V matches)
    short8 pf[2][2];
#pragma unroll
    for (int sub = 0; sub < 2; ++sub)
#pragma unroll
      for (int kh = 0; kh < 2; ++kh) {
        ushort_t tmp[8];
#pragma unroll
        for (int half = 0; half < 2; ++half)
#pragma unroll
          for (int r = 0; r < 4; ++r)
            tmp[half * 4 + r] = f2bf_hu(s[sub][2 * kh + half][r]);
        pf[sub][kh] = *(short8*)tmp;
      }

    // O += P V (V pre-permuted to pi2); l += P 1
    __builtin_amdgcn_s_setprio(1);
#pragma unroll
    for (int sub = 0; sub < 2; ++sub) {
#pragma unroll
      for (int ht = 0; ht < 4; ++ht) {
        o[sub][ht] = __builtin_amdgcn_mfma_f32_16x16x32_bf16(pf[sub][0], vf[ht * 2],     o[sub][ht], 0, 0, 0);
        o[sub][ht] = __builtin_amdgcn_mfma_f32_16x16x32_bf16(pf[sub][1], vf[ht * 2 + 1], o[sub][ht], 0, 0, 0);
      }
      ol[sub] = __builtin_amdgcn_mfma_f32_16x16x32_bf16(pf[sub][0], ones, ol[sub], 0, 0, 0);
      ol[sub] = __builtin_amdgcn_mfma_f32_16x16x32_bf16(pf[sub][1], ones, ol[sub], 0, 0, 0);
    }
    __builtin_amdgcn_s_setprio(0);
  }

  // ---- merge 4 waves' partials (plain sums; max-free) ----
#pragma unroll
  for (int sub = 0; sub < 2; ++sub) {
#pragma unroll
    for (int ht = 0; ht < 4; ++ht)
#pragma unroll
      for (int r = 0; r < 4; ++r)
        Om[wv][sub][quad * 4 + r][ht * 16 + col] = o[sub][ht][r];
    if (col == 0) {
#pragma unroll
      for (int r = 0; r < 4; ++r) Ml[wv][sub][quad * 4 + r] = ol[sub][r];
    }
  }
  __syncthreads();

  const int rr = tid >> 4, h4 = (tid & 15) * 4;
#pragma unroll
  for (int sub = 0; sub < 2; ++sub) {
    float L = (Ml[0][sub][rr] + Ml[1][sub][rr]) + (Ml[2][sub][rr] + Ml[3][sub][rr]);
    float4 a; a.x = 0.f; a.y = 0.f; a.z = 0.f; a.w = 0.f;
#pragma unroll
    for (int w = 0; w < 4; ++w) {
      float4 ov = *(const float4*)&Om[w][sub][rr][h4];
      a.x += ov.x; a.y += ov.y; a.z += ov.z; a.w += ov.w;
    }
    float inv = 1.f / L;
    a.x *= inv; a.y *= inv; a.z *= inv; a.w *= inv;
    *(float4*)(out + (size_t)(b * Tn + g * 32 + sub * 16 + rr) * Hn + h4) = a;
  }
}

extern "C" void kernel_launch(void* const* d_in, const int* in_sizes, int n_in,
                              void* d_out, int out_size, void* d_ws, size_t ws_size,
                              hipStream_t stream) {
  const float* x  = (const float*)d_in[0];
  const float* Wq = (const float*)d_in[1];
  const float* Wk = (const float*)d_in[2];
  const float* Wv = (const float*)d_in[3];
  float* out = (float*)d_out;

  ushort_t* Qf = (ushort_t*)d_ws;                   // 2 MB frag-major (pre-scaled)
  ushort_t* Kf = Qf + (size_t)Bn * Tn * Hn;         // 2 MB
  ushort_t* Vf = Kf + (size_t)Bn * Tn * Hn;         // 2 MB (pi2-permuted keys)
  ushort_t* Wf = Vf + (size_t)Bn * Tn * Hn;         // 384 KB

  wf_kernel<<<dim3(96), dim3(256), 0, stream>>>(Wq, Wk, Wv, Wf);
  qkv_proj_kernel<<<dim3(256), dim3(256), 0, stream>>>(x, Wf, Qf, Kf, Vf);
  attn_kernel<<<dim3(Bn * 128), dim3(256), 0, stream>>>(Qf, Kf, Vf, out);
}

// Round 11
// 123.065 us; speedup vs baseline: 1.0301x; 1.0212x over previous
//
#include <hip/hip_runtime.h>
#include <math.h>

#define Bn 4
#define Tn 4096
#define Cn 1024
#define Hn 64

typedef __attribute__((ext_vector_type(8))) short short8;
typedef __attribute__((ext_vector_type(4))) float floatx4;
typedef unsigned short ushort_t;

// 0.125 (H^-0.5) * log2(e): folded into Q so attn uses native exp2
#define QSCALE 0.1803368801111204f

// Compiler fence (R7/R8 lesson: hipcc re-serializes register load batches to
// minimal pressure; fence keeps issued batches batched. R8 measured best.)
#define ILP_FENCE() asm volatile("" ::: "memory")

__device__ __forceinline__ ushort_t f2bf(float f) {       // RNE
  union { float f; unsigned u; } v; v.f = f;
  unsigned r = v.u + 0x7FFFu + ((v.u >> 16) & 1u);
  return (ushort_t)(r >> 16);
}
__device__ __forceinline__ ushort_t f2bf_hu(float f) {    // round-half-up (P only)
  union { float f; unsigned u; } v; v.f = f;
  return (ushort_t)((v.u + 0x8000u) >> 16);
}
__device__ __forceinline__ float bf2f(ushort_t h) {
  union { unsigned u; float f; } v; v.u = ((unsigned)h) << 16; return v.f;
}

// ---------------------------------------------------------------------------
// R11 = R8 exact revert (best measured 123.5us). R9 (DMA+16-row) and R10
// (64-row/1-block-per-CU) both regressed; their hypotheses are falsified:
// - FETCH_SIZE is row-count-invariant (Wf is L2-resident; x dominates HBM).
// - qkv needs >=8 waves/CU; TLP is the binding resource, not intensity.
// - Total wall is pinned 123-130 across 60% qkv swings: harness envelope
//   (268MB poison fill @41us + ramp) absorbs kernel deltas.
// Layouts (lane = (quad=lane>>4, col=lane&15)):
//  Qf/Kf[b][s=t/16][half=h/32]: lane holds h = half*32+quad*8+e for t=s*16+col.
//  Vf[b][i=t/64][ht=h/16][kh]: lane reg e holds V[t=i*64+pi2(kh,quad,e)][ht*16+col],
//    pi2 = 32*kh + 16*(e>>2) + 4*quad + (e&3) -- matches swapped-QK P layout
//    so P feeds PV's A-fragment from registers (no LDS in attn main loop).
//  Wf[m][g=c/32][nt=h/16]: lane holds W[c=g*32+quad*8+e][h=nt*16+col].
// ---------------------------------------------------------------------------

// W^T -> fragment-major bf16. grid = 96 (m*32+g), 256 threads.
__global__ __launch_bounds__(256) void wf_kernel(
    const float* __restrict__ Wq, const float* __restrict__ Wk,
    const float* __restrict__ Wv, ushort_t* __restrict__ Wf)
{
  __shared__ float ws[32][65];
  const int tid = threadIdx.x;
  const int m = blockIdx.x >> 5;
  const int g = blockIdx.x & 31;
  const float* W = (m == 0) ? Wq : (m == 1) ? Wk : Wv;
  const float4* src = (const float4*)(W + (size_t)g * 32 * Hn);
#pragma unroll
  for (int it = 0; it < 2; ++it) {
    int i4 = it * 256 + tid;
    float4 v = src[i4];
    int c = i4 >> 4, h = (i4 & 15) * 4;
    ws[c][h] = v.x; ws[c][h + 1] = v.y; ws[c][h + 2] = v.z; ws[c][h + 3] = v.w;
  }
  __syncthreads();
  const int nt = tid >> 6, lane = tid & 63;
  const int col = lane & 15, quad = lane >> 4;
  ushort_t t[8];
#pragma unroll
  for (int e = 0; e < 8; ++e) t[e] = f2bf(ws[quad * 8 + e][nt * 16 + col]);
  *(short8*)(Wf + ((size_t)((m * 32 + g) * 4 + nt) * 64 + lane) * 8) = *(short8*)t;
}

// ---------------------------------------------------------------------------
// QKV projection. grid = 512 x 256; block owns 32 rows (2 subtiles), 4 waves
// K-split (256 ch each). Staging in two fenced 16-load batches; K-loop per ch:
// fenced 12-load Wf batch + 2 LDS af reads -> 24-MFMA cluster.
// Epilogue: partials to LDS bf16 (STATIC acc indexing), per-wave reduce,
// frag-image staging, coalesced copy-out. 3 barriers/block.
// ---------------------------------------------------------------------------
__global__ __launch_bounds__(256, 2) void qkv_proj_kernel(
    const float* __restrict__ x, const ushort_t* __restrict__ Wf,
    ushort_t* __restrict__ Qf, ushort_t* __restrict__ Kf,
    ushort_t* __restrict__ Vf)
{
  __shared__ __align__(16) char smem[67584];
  ushort_t* xs  = (ushort_t*)smem;              // [4 wv][32 row][264] bf16 (67584 B)
  ushort_t* red = (ushort_t*)smem;              // overlays xs: [24][4][64][4] (49152 B)
  ushort_t* img = (ushort_t*)(smem + 49152);    // Q[2][1024] K[2][1024] V[4][512]

  const int tid  = threadIdx.x;
  const int wv   = tid >> 6;
  const int lane = tid & 63;
  const int col  = lane & 15;
  const int quad = lane >> 4;
  const int blk  = blockIdx.x;
  const int row0 = blk * 32;

  // ---- stage wave's x slice (32 rows x 256 ch): 2 fenced 16-load batches ----
#pragma unroll
  for (int half = 0; half < 2; ++half) {
    float4 v[16];
#pragma unroll
    for (int jj = 0; jj < 16; ++jj)
      v[jj] = *(const float4*)(x + (size_t)(row0 + half * 16 + jj) * Cn + wv * 256 + lane * 4);
    ILP_FENCE();   // all 16 loads issued & live before any LDS store
#pragma unroll
    for (int jj = 0; jj < 16; ++jj) {
      ushort4 u;
      u.x = f2bf(v[jj].x); u.y = f2bf(v[jj].y); u.z = f2bf(v[jj].z); u.w = f2bf(v[jj].w);
      *(ushort4*)(xs + (wv * 32 + half * 16 + jj) * 264 + lane * 4) = u;
    }
  }
  // wave reads only its own slice -> no barrier (lgkmcnt orders same-wave LDS)

  floatx4 acc[2][3][4];
#pragma unroll
  for (int sub = 0; sub < 2; ++sub)
#pragma unroll
    for (int m = 0; m < 3; ++m)
#pragma unroll
      for (int nt = 0; nt < 4; ++nt) {
        acc[sub][m][nt][0] = 0.f; acc[sub][m][nt][1] = 0.f;
        acc[sub][m][nt][2] = 0.f; acc[sub][m][nt][3] = 0.f;
      }

  // ---- K-loop: 8 x 32ch; fenced 12-load Wf batch + af, then MFMA cluster ----
#pragma unroll
  for (int ch = 0; ch < 8; ++ch) {
    const int gg = wv * 8 + ch;                 // global 32-ch chunk
    short8 bf[12];
#pragma unroll
    for (int k = 0; k < 12; ++k) {
      const int m_ = k >> 2, nt_ = k & 3;
      bf[k] = *(const short8*)(Wf + ((size_t)((m_ * 32 + gg) * 4 + nt_) * 64 + lane) * 8);
    }
    short8 af0 = *(const short8*)(xs + (wv * 32 + col) * 264 + ch * 32 + quad * 8);
    short8 af1 = *(const short8*)(xs + (wv * 32 + 16 + col) * 264 + ch * 32 + quad * 8);
    ILP_FENCE();   // 12 global + 2 LDS loads all in flight before compute
#pragma unroll
    for (int k = 0; k < 12; ++k) {
      const int m_ = k >> 2, nt_ = k & 3;
      acc[0][m_][nt_] = __builtin_amdgcn_mfma_f32_16x16x32_bf16(af0, bf[k], acc[0][m_][nt_], 0, 0, 0);
      acc[1][m_][nt_] = __builtin_amdgcn_mfma_f32_16x16x32_bf16(af1, bf[k], acc[1][m_][nt_], 0, 0, 0);
    }
  }
  __syncthreads();   // xs reads done everywhere; safe to overlay red

  // ---- dump ALL partials to LDS (static acc indices; lane-contiguous 8B) ----
#pragma unroll
  for (int sub = 0; sub < 2; ++sub)
#pragma unroll
    for (int m = 0; m < 3; ++m)
#pragma unroll
      for (int nt = 0; nt < 4; ++nt) {
        const int p = (sub * 3 + m) * 4 + nt;
        ushort4 u;
        u.x = f2bf(acc[sub][m][nt][0]); u.y = f2bf(acc[sub][m][nt][1]);
        u.z = f2bf(acc[sub][m][nt][2]); u.w = f2bf(acc[sub][m][nt][3]);
        *(ushort4*)&red[((p * 4 + wv) * 64 + lane) * 4] = u;
      }
  __syncthreads();

  // ---- wave wv reduces p in [6wv, 6wv+6) from LDS; writes frag-images ----
#pragma unroll
  for (int pp = 0; pp < 6; ++pp) {
    const int p = wv * 6 + pp;
    ushort4 w0 = *(const ushort4*)&red[((p * 4 + 0) * 64 + lane) * 4];
    ushort4 w1 = *(const ushort4*)&red[((p * 4 + 1) * 64 + lane) * 4];
    ushort4 w2 = *(const ushort4*)&red[((p * 4 + 2) * 64 + lane) * 4];
    ushort4 w3 = *(const ushort4*)&red[((p * 4 + 3) * 64 + lane) * 4];
    float v[4];
    v[0] = (bf2f(w0.x) + bf2f(w1.x)) + (bf2f(w2.x) + bf2f(w3.x));
    v[1] = (bf2f(w0.y) + bf2f(w1.y)) + (bf2f(w2.y) + bf2f(w3.y));
    v[2] = (bf2f(w0.z) + bf2f(w1.z)) + (bf2f(w2.z) + bf2f(w3.z));
    v[3] = (bf2f(w0.w) + bf2f(w1.w)) + (bf2f(w2.w) + bf2f(w3.w));
    const int sub = (p >= 12) ? 1 : 0;
    const int mrem = p - sub * 12;
    const int m = mrem >> 2, nt = mrem & 3;
#pragma unroll
    for (int r = 0; r < 4; ++r) {
      const int tlq = quad * 4 + r;
      if (m == 2) {
        // V image for swapped-QK attn: slot (quad, e=sub*4+r) holds local key
        // 16*sub + 4*quad + r  (pi2 with kh supplied by the copy-out's g&1)
        img[4096 + nt * 512 + (quad * 16 + col) * 8 + sub * 4 + r] = f2bf(v[r]);
      } else {
        const int h = nt * 16 + col;
        const int idx = (h >> 5) * 512 + ((h >> 3) & 3) * 128 + tlq * 8 + (h & 7);
        img[m * 2048 + sub * 1024 + idx] = f2bf(m == 0 ? v[r] * QSCALE : v[r]);
      }
    }
  }
  __syncthreads();

  // ---- coalesced copy-out ----
  {
    const int b = blk >> 7, g = blk & 127;
#pragma unroll
    for (int sub = 0; sub < 2; ++sub) {
      const size_t qg = (size_t)(b * 256 + 2 * g + sub) * 1024 + tid * 4;
      *(uint2*)(Qf + qg) = *(const uint2*)&img[sub * 1024 + tid * 4];
      *(uint2*)(Kf + qg) = *(const uint2*)&img[2048 + sub * 1024 + tid * 4];
    }
    const int ht = tid >> 6;
    const size_t vg = ((size_t)(b * 64 + (g >> 1)) * 8 + ht * 2 + (g & 1)) * 512 + (tid & 63) * 8;
    *(short8*)(Vf + vg) = *(const short8*)&img[4096 + ht * 512 + (tid & 63) * 8];
  }
}

// ---------------------------------------------------------------------------
// Flash attention, causal, max-free softmax. grid = B*128 (32-row q-tiles).
// g remap balances per-CU work. 4 waves stride 64-key tiles with private
// (O,l). SWAPPED QK^T keeps P entirely in registers; one fenced 16-load K/V
// batch per tile; zero barriers in the main loop.
// ---------------------------------------------------------------------------
__global__ __launch_bounds__(256, 2) void attn_kernel(
    const ushort_t* __restrict__ Qf, const ushort_t* __restrict__ Kf,
    const ushort_t* __restrict__ Vf, float* __restrict__ out)
{
  __shared__ __align__(16) float Om[4][2][16][68];
  __shared__ __align__(16) float Ml[4][2][16];

  const int tid  = threadIdx.x;
  const int wv   = tid >> 6;
  const int lane = tid & 63;
  const int col  = lane & 15;
  const int quad = lane >> 4;
  const int b   = blockIdx.x & 3;
  const int idx = blockIdx.x >> 2;                          // 0..127
  const int g   = (idx < 64) ? (127 - 2 * idx) : (2 * (idx - 64));  // balanced remap

  short8 qf[2][2];
#pragma unroll
  for (int sub = 0; sub < 2; ++sub)
#pragma unroll
    for (int half = 0; half < 2; ++half)
      qf[sub][half] = *(const short8*)(Qf + (size_t)(b * 256 + 2 * g + sub) * 1024 + half * 512 + lane * 8);

  const ushort_t* Kbase = Kf + (size_t)b * 256 * 1024;
  const ushort_t* Vbase = Vf + (size_t)b * 64 * 8 * 512;

  short8 ones;
#pragma unroll
  for (int e = 0; e < 8; ++e) ones[e] = (short)0x3F80;  // bf16 1.0

  floatx4 o[2][4], ol[2];
#pragma unroll
  for (int sub = 0; sub < 2; ++sub) {
#pragma unroll
    for (int ht = 0; ht < 4; ++ht) { o[sub][ht][0]=0.f; o[sub][ht][1]=0.f; o[sub][ht][2]=0.f; o[sub][ht][3]=0.f; }
    ol[sub][0]=0.f; ol[sub][1]=0.f; ol[sub][2]=0.f; ol[sub][3]=0.f;
  }

  const int ntile = ((g * 32 + 31) >> 6) + 1;
  const int dtile = ntile - 1;

  for (int i = wv; i < ntile; i += 4) {
    // ---- one fenced batch: all 8 K + 8 V fragments of tile i in flight ----
    short8 kf[8], vf[8];
#pragma unroll
    for (int kt = 0; kt < 4; ++kt) {
      const ushort_t* kp = Kbase + (size_t)i * 4096 + kt * 1024 + lane * 8;
      kf[kt * 2]     = *(const short8*)(kp);
      kf[kt * 2 + 1] = *(const short8*)(kp + 512);
    }
#pragma unroll
    for (int ht = 0; ht < 4; ++ht) {
#pragma unroll
      for (int kh = 0; kh < 2; ++kh)
        vf[ht * 2 + kh] = *(const short8*)(Vbase + ((size_t)i * 8 + ht * 2 + kh) * 512 + lane * 8);
    }
    ILP_FENCE();

    // S^T = K Q^T (swapped): lane(quad,col) reg r of s[sub][kt] holds
    // S[key = 64i+16kt+4quad+r][q = g*32+sub*16+col]
    floatx4 s[2][4];
    __builtin_amdgcn_s_setprio(1);
#pragma unroll
    for (int sub = 0; sub < 2; ++sub)
#pragma unroll
      for (int kt = 0; kt < 4; ++kt) {
        floatx4 c; c[0]=0.f; c[1]=0.f; c[2]=0.f; c[3]=0.f;
        c = __builtin_amdgcn_mfma_f32_16x16x32_bf16(kf[kt * 2],     qf[sub][0], c, 0, 0, 0);
        c = __builtin_amdgcn_mfma_f32_16x16x32_bf16(kf[kt * 2 + 1], qf[sub][1], c, 0, 0, 0);
        s[sub][kt] = c;
      }
    __builtin_amdgcn_s_setprio(0);

    if (i == dtile) {   // causal mask on diagonal tile (exp2(-inf)=0)
#pragma unroll
      for (int sub = 0; sub < 2; ++sub)
#pragma unroll
        for (int kt = 0; kt < 4; ++kt)
#pragma unroll
          for (int r = 0; r < 4; ++r)
            if (64 * i + kt * 16 + quad * 4 + r > g * 32 + sub * 16 + col)
              s[sub][kt][r] = -INFINITY;
    }

#pragma unroll
    for (int sub = 0; sub < 2; ++sub)
#pragma unroll
      for (int kt = 0; kt < 4; ++kt)
#pragma unroll
        for (int r = 0; r < 4; ++r)
          s[sub][kt][r] = __builtin_amdgcn_exp2f(s[sub][kt][r]);

    // pack P to bf16 A-fragments IN REGISTERS (key order = pi2, V matches)
    short8 pf[2][2];
#pragma unroll
    for (int sub = 0; sub < 2; ++sub)
#pragma unroll
      for (int kh = 0; kh < 2; ++kh) {
        ushort_t tmp[8];
#pragma unroll
        for (int half = 0; half < 2; ++half)
#pragma unroll
          for (int r = 0; r < 4; ++r)
            tmp[half * 4 + r] = f2bf_hu(s[sub][2 * kh + half][r]);
        pf[sub][kh] = *(short8*)tmp;
      }

    // O += P V (V pre-permuted to pi2); l += P 1
    __builtin_amdgcn_s_setprio(1);
#pragma unroll
    for (int sub = 0; sub < 2; ++sub) {
#pragma unroll
      for (int ht = 0; ht < 4; ++ht) {
        o[sub][ht] = __builtin_amdgcn_mfma_f32_16x16x32_bf16(pf[sub][0], vf[ht * 2],     o[sub][ht], 0, 0, 0);
        o[sub][ht] = __builtin_amdgcn_mfma_f32_16x16x32_bf16(pf[sub][1], vf[ht * 2 + 1], o[sub][ht], 0, 0, 0);
      }
      ol[sub] = __builtin_amdgcn_mfma_f32_16x16x32_bf16(pf[sub][0], ones, ol[sub], 0, 0, 0);
      ol[sub] = __builtin_amdgcn_mfma_f32_16x16x32_bf16(pf[sub][1], ones, ol[sub], 0, 0, 0);
    }
    __builtin_amdgcn_s_setprio(0);
  }

  // ---- merge 4 waves' partials (plain sums; max-free) ----
#pragma unroll
  for (int sub = 0; sub < 2; ++sub) {
#pragma unroll
    for (int ht = 0; ht < 4; ++ht)
#pragma unroll
      for (int r = 0; r < 4; ++r)
        Om[wv][sub][quad * 4 + r][ht * 16 + col] = o[sub][ht][r];
    if (col == 0) {
#pragma unroll
      for (int r = 0; r < 4; ++r) Ml[wv][sub][quad * 4 + r] = ol[sub][r];
    }
  }
  __syncthreads();

  const int rr = tid >> 4, h4 = (tid & 15) * 4;
#pragma unroll
  for (int sub = 0; sub < 2; ++sub) {
    float L = (Ml[0][sub][rr] + Ml[1][sub][rr]) + (Ml[2][sub][rr] + Ml[3][sub][rr]);
    float4 a; a.x = 0.f; a.y = 0.f; a.z = 0.f; a.w = 0.f;
#pragma unroll
    for (int w = 0; w < 4; ++w) {
      float4 ov = *(const float4*)&Om[w][sub][rr][h4];
      a.x += ov.x; a.y += ov.y; a.z += ov.z; a.w += ov.w;
    }
    float inv = 1.f / L;
    a.x *= inv; a.y *= inv; a.z *= inv; a.w *= inv;
    *(float4*)(out + (size_t)(b * Tn + g * 32 + sub * 16 + rr) * Hn + h4) = a;
  }
}

extern "C" void kernel_launch(void* const* d_in, const int* in_sizes, int n_in,
                              void* d_out, int out_size, void* d_ws, size_t ws_size,
                              hipStream_t stream) {
  const float* x  = (const float*)d_in[0];
  const float* Wq = (const float*)d_in[1];
  const float* Wk = (const float*)d_in[2];
  const float* Wv = (const float*)d_in[3];
  float* out = (float*)d_out;

  ushort_t* Qf = (ushort_t*)d_ws;                   // 2 MB frag-major (pre-scaled)
  ushort_t* Kf = Qf + (size_t)Bn * Tn * Hn;         // 2 MB
  ushort_t* Vf = Kf + (size_t)Bn * Tn * Hn;         // 2 MB (pi2-permuted keys)
  ushort_t* Wf = Vf + (size_t)Bn * Tn * Hn;         // 384 KB

  wf_kernel<<<dim3(96), dim3(256), 0, stream>>>(Wq, Wk, Wv, Wf);
  qkv_proj_kernel<<<dim3(512), dim3(256), 0, stream>>>(x, Wf, Qf, Kf, Vf);
  attn_kernel<<<dim3(Bn * 128), dim3(256), 0, stream>>>(Qf, Kf, Vf, out);
}